// Round 19
// baseline (200.623 us; speedup 1.0000x reference)
//
#include <hip/hip_runtime.h>
#include <stdint.h>

#define DIM   2048
#define LSEQ  2048
#define BATCH 2
#define NH    32
#define NKV   8
#define HD    64
#define M_ROWS (BATCH*LSEQ)       // 4096
#define NQKV  (DIM + 2*NKV*HD)    // 3072
#define KOFF  DIM                 // 2048
#define VOFF  (DIM + NKV*HD)      // 2560

typedef __attribute__((ext_vector_type(8))) __bf16 bf16x8;
typedef __attribute__((ext_vector_type(8))) unsigned short u16x8;
typedef __attribute__((ext_vector_type(4))) float f32x4;

// hardware RNE f32->bf16 (harness-verified rounds 2-18)
__device__ __forceinline__ unsigned short f2bf(float f) {
  union { __bf16 h; unsigned short u; } v;
  v.h = (__bf16)f;
  return v.u;
}
__device__ __forceinline__ float bf2f(unsigned short h) {
  union { unsigned u; float f; } v; v.u = ((unsigned)h) << 16;
  return v.f;
}

__device__ __forceinline__ void gload_lds16(const void* g, void* l) {
  __builtin_amdgcn_global_load_lds(
      (__attribute__((address_space(1))) unsigned int*)g,
      (__attribute__((address_space(3))) unsigned int*)l, 16, 0, 0);
}

// ---------------- fp32 -> bf16 convert (vectorized) ----------------
__global__ void k_cvt_x(const float* __restrict__ in, unsigned short* __restrict__ out, int n4) {
  int i = blockIdx.x * blockDim.x + threadIdx.x;
  if (i >= n4) return;
  float4 v = ((const float4*)in)[i];
  ushort4 o;
  o.x = f2bf(v.x); o.y = f2bf(v.y); o.z = f2bf(v.z); o.w = f2bf(v.w);
  ((ushort4*)out)[i] = o;
}

// ---------------- fused weight transposes + RoPE tables: 5 z-sections (r18-verified) ----------------
__global__ void k_transpose_all(const float* __restrict__ wq, const float* __restrict__ wk,
                                const float* __restrict__ wv, const float* __restrict__ wo,
                                unsigned short* __restrict__ wqkvT,
                                unsigned short* __restrict__ woT,
                                float* __restrict__ cosT, float* __restrict__ sinT,
                                float C2) {
  int sec = blockIdx.z;
  if (sec == 4) {   // RoPE tables: idx < 256 blocks x 256 threads = LSEQ*32 elements
    int idx = blockIdx.y * 64 + blockIdx.x;
    if (idx >= 256) return;
    int i = idx * 256 + threadIdx.y * 32 + threadIdx.x;
    int tpos = i >> 5, j = i & 31;
    float inv = powf(10000.0f, -(float)j / 32.0f);
    float fr = (float)tpos * inv;
    cosT[i] = cosf(fr);
    sinT[i] = sinf(fr);
    return;
  }
  __shared__ float tile[32][33];
  const float* in; unsigned short* out; int N; float scale = 1.0f;
  if (sec == 0)      { in = wq; out = wqkvT;                     N = DIM; scale = C2; }
  else if (sec == 1) { in = wk; out = wqkvT + (long)2048 * 2048; N = 512; }
  else if (sec == 2) { in = wv; out = wqkvT + (long)2560 * 2048; N = 512; }
  else               { in = wo; out = woT;                       N = DIM; }
  int n0 = blockIdx.x * 32;
  if (n0 >= N) return;
  int k0 = blockIdx.y * 32;
  int tx = threadIdx.x, ty = threadIdx.y;
  #pragma unroll
  for (int i = ty; i < 32; i += 8)
    tile[i][tx] = in[(long)(k0 + i) * N + n0 + tx];
  __syncthreads();
  #pragma unroll
  for (int i = ty; i < 32; i += 8)
    out[(long)(n0 + i) * DIM + k0 + tx] = f2bf(scale * tile[tx][i]);
}

// ---------------- transpose V section of qkv -> vT, k-PERMUTED columns (r6-verified) ----------------
__global__ void k_transpose_v(const unsigned short* __restrict__ qkv,
                              unsigned short* __restrict__ vT) {
  __shared__ unsigned short tile[32][33];
  int c0 = blockIdx.x * 32;   // within 512 (= g*64+d)
  int l0 = blockIdx.y * 32;
  int b  = blockIdx.z;
  int tx = threadIdx.x, ty = threadIdx.y;
  #pragma unroll
  for (int i = ty; i < 32; i += 8)
    tile[i][tx] = qkv[((long)b * LSEQ + l0 + i) * NQKV + VOFF + c0 + tx];
  __syncthreads();
  int e = 8 * ((tx >> 2) & 3) + 4 * (tx >> 4) + (tx & 3);
  #pragma unroll
  for (int i = ty; i < 32; i += 8)
    vT[((long)b * 512 + c0 + i) * LSEQ + l0 + e] = tile[tx][i];
}

// ---------------- GEMM v8 (QKV): 128^2 tile, BK=64, 512 thr / 8 waves (r13-verified) ----------------
template<bool BF16OUT, bool ROPE>
__global__ __launch_bounds__(512, 4) void k_gemm_bt(
    const unsigned short* __restrict__ A, const unsigned short* __restrict__ Bt,
    void* __restrict__ Cv, int M, int N, int K,
    const float* __restrict__ cosT, const float* __restrict__ sinT) {
  __shared__ __align__(16) char AsB[16384];   // [128 rows][128B], swizzled
  __shared__ __align__(16) char BsB[16384];
  int t = threadIdx.x;
  int lane = t & 63, wave = t >> 6;        // 0..7
  int fr = lane & 15, fg = lane >> 4;
  int wm = wave >> 1, wn = wave & 1;       // 4M x 2N quadrants: 32 rows x 64 cols
  long rowA = (long)blockIdx.x * 128;
  long rowB = (long)blockIdx.y * 128;
  long K2 = (long)K * 2;

  int scol = ((t & 7) * 16) ^ (((t >> 3) & 7) << 4);
  const char* ApB = (const char*)A  + (rowA + (t >> 3)) * K2 + scol;
  const char* BpB = (const char*)Bt + (rowB + (t >> 3)) * K2 + scol;

  f32x4 acc[2][4] = {};
  int sw8 = (fr & 7) << 4;

  for (int kt = 0; kt < K; kt += 64) {
    #pragma unroll
    for (int p = 0; p < 2; p++) {
      gload_lds16(ApB + (long)(p * 64) * K2 + kt * 2, AsB + p * 8192 + t * 16);
      gload_lds16(BpB + (long)(p * 64) * K2 + kt * 2, BsB + p * 8192 + t * 16);
    }
    __syncthreads();
    #pragma unroll
    for (int ks = 0; ks < 2; ks++) {
      bf16x8 af[2], bfv[4];
      #pragma unroll
      for (int i = 0; i < 2; i++)
        af[i] = *(const bf16x8*)(AsB + (wm * 32 + i * 16 + fr) * 128 + ((ks * 64 + fg * 16) ^ sw8));
      #pragma unroll
      for (int j = 0; j < 4; j++)
        bfv[j] = *(const bf16x8*)(BsB + (wn * 64 + j * 16 + fr) * 128 + ((ks * 64 + fg * 16) ^ sw8));
      #pragma unroll
      for (int i = 0; i < 2; i++) {
        #pragma unroll
        for (int j = 0; j < 4; j++)
          acc[i][j] = __builtin_amdgcn_mfma_f32_16x16x32_bf16(af[i], bfv[j], acc[i][j], 0, 0, 0);
      }
    }
    __syncthreads();
  }

  long colbase = rowB + wn * 64;
  bool rope_sec = ROPE && (colbase < VOFF);   // Q or K head (col < 2560); wave-uniform
  #pragma unroll
  for (int i = 0; i < 2; i++) {
    #pragma unroll
    for (int r = 0; r < 4; r++) {
      long row = rowA + wm * 32 + i * 16 + fg * 4 + r;
      if (ROPE && rope_sec) {
        int tpos = (int)(row & (LSEQ - 1));
        #pragma unroll
        for (int j = 0; j < 2; j++) {   // pair (d = j*16+fr, d+32 = (j+2)*16+fr)
          int jj = j * 16 + fr;
          float c = cosT[tpos * 32 + jj];
          float s = sinT[tpos * 32 + jj];
          float lo = acc[i][j][r], hi = acc[i][j + 2][r];
          ((unsigned short*)Cv)[row * N + colbase + j * 16 + fr]       = f2bf(lo * c - hi * s);
          ((unsigned short*)Cv)[row * N + colbase + (j + 2) * 16 + fr] = f2bf(hi * c + lo * s);
        }
      } else {
        #pragma unroll
        for (int j = 0; j < 4; j++) {
          long col = colbase + j * 16 + fr;
          if (BF16OUT) ((unsigned short*)Cv)[row * N + col] = f2bf(acc[i][j][r]);
          else         ((float*)Cv)[row * N + col] = acc[i][j][r];
        }
      }
    }
  }
}

// ---------------- GEMM v9 (WO): 128^2 dbuf single-barrier pipeline, 512 threads (r13-verified) ----------------
__global__ __launch_bounds__(512, 4) void k_gemm_db(
    const unsigned short* __restrict__ A, const unsigned short* __restrict__ Bt,
    float* __restrict__ Cv, int M, int N, int K) {
  __shared__ __align__(16) char AsB[2][16384];   // [buf][128 rows][128B], swizzled
  __shared__ __align__(16) char BsB[2][16384];
  int t = threadIdx.x;
  int lane = t & 63, wave = t >> 6;
  int fr = lane & 15, fg = lane >> 4;
  int wm = wave >> 1, wn = wave & 1;       // 4M x 2N quadrants: 32 rows x 64 cols
  long rowA = (long)blockIdx.x * 128;
  long rowB = (long)blockIdx.y * 128;
  long K2 = (long)K * 2;

  int scol = ((t & 7) * 16) ^ (((t >> 3) & 7) << 4);
  const char* ApB = (const char*)A  + (rowA + (t >> 3)) * K2 + scol;
  const char* BpB = (const char*)Bt + (rowB + (t >> 3)) * K2 + scol;

  auto stage = [&](int kt, int bi) {   // kt in 64-elem tiles; 4 loads/thread
    #pragma unroll
    for (int p = 0; p < 2; p++) {
      gload_lds16(ApB + (long)(p * 64) * K2 + (long)kt * 128, AsB[bi] + p * 8192 + t * 16);
      gload_lds16(BpB + (long)(p * 64) * K2 + (long)kt * 128, BsB[bi] + p * 8192 + t * 16);
    }
  };

  f32x4 acc[2][4] = {};
  int sw8 = (fr & 7) << 4;
  int NT = K >> 6;

  stage(0, 0);
  for (int kt = 0; kt < NT; kt++) {
    int cur = kt & 1;
    asm volatile("s_waitcnt vmcnt(0)" ::: "memory");
    __builtin_amdgcn_s_barrier();
    __builtin_amdgcn_sched_barrier(0);
    const char* Ac = AsB[cur];
    const char* Bc = BsB[cur];
    #pragma unroll
    for (int ks = 0; ks < 2; ks++) {
      bf16x8 af[2], bfv[4];
      #pragma unroll
      for (int i = 0; i < 2; i++)
        af[i] = *(const bf16x8*)(Ac + (wm * 32 + i * 16 + fr) * 128 + ((ks * 64 + fg * 16) ^ sw8));
      #pragma unroll
      for (int j = 0; j < 4; j++)
        bfv[j] = *(const bf16x8*)(Bc + (wn * 64 + j * 16 + fr) * 128 + ((ks * 64 + fg * 16) ^ sw8));
      if (ks == 0 && kt + 1 < NT) stage(kt + 1, cur ^ 1);   // issue under reads+MFMA
      #pragma unroll
      for (int i = 0; i < 2; i++) {
        #pragma unroll
        for (int j = 0; j < 4; j++)
          acc[i][j] = __builtin_amdgcn_mfma_f32_16x16x32_bf16(af[i], bfv[j], acc[i][j], 0, 0, 0);
      }
    }
  }

  #pragma unroll
  for (int i = 0; i < 2; i++) {
    #pragma unroll
    for (int j = 0; j < 4; j++) {
      #pragma unroll
      for (int r = 0; r < 4; r++) {
        long row = rowA + wm * 32 + i * 16 + fg * 4 + r;
        long col = rowB + wn * 64 + j * 16 + fr;
        Cv[row * N + col] = acc[i][j][r];
      }
    }
  }
}

// ---------------- flash attention v20: single-buffered V -> 32KB LDS, 4 blocks/CU ----------------
// Round-19: flash is latency-bound at ~2 resident blocks/CU (Occ 25.5, MfmaUtil 26).
// LDS 48->32KB by single-buffering V raises residency to 4 blocks/CU (grid 1024 = 4/CU,
// VGPR 84 < 128 cap). Schedule (each piece individually proven):
//   B1 = vmcnt(4) + raw s_barrier + sched_barrier(0)  [r3-tested]: waits K (+Q at iter
//        0; vmcnt drains oldest-first), leaves V's 4 loads in flight across QK.
//   B2 = __syncthreads (implicit vmcnt(0)): drains V before PV; V cover = issue(B3 of
//        prev iter) -> B2 spans B1+QK. stageK(kt+1) stays after B2 (unchanged).
//   B3 = __syncthreads after PV, then stageV(kt+1) into the SAME buffer -- WAR-safe
//        (all waves' PV reads retired at B3).
// Cross-wave visibility: every wave's staged writes are vmcnt-drained before it passes
// the barrier its readers wait behind. CFG straight-line; causal mask stays loop-uniform
// (kt==qt) -- the r15/r16 spill trigger is absent. Cost +1 barrier/iter.
__global__ __launch_bounds__(256, 4) void k_flash_attn17(
    const unsigned short* __restrict__ qkv, const unsigned short* __restrict__ vT,
    unsigned short* __restrict__ attn) {
  int g0 = (int)blockIdx.x;
  int hb = g0 & 63;
  int h = hb & 31, b = hb >> 5;
  int qt = 15 - (g0 >> 6);            // heavy blocks first (backfill smooths the tail)
  int g = h >> 2;
  int t = threadIdx.x, lane = t & 63, wave = t >> 6;
  int fr = lane & 15, fg = lane >> 4;

  __shared__ __align__(16) char KT[16384];   // 16KB: K tile [128 rows][128B], swz
  __shared__ __align__(16) char VT[16384];   // 16KB: V tile [64 rows][256B], swz, SINGLE buf
  long rowbase = (long)b * LSEQ;

  int qbaseA = qt * 128 + wave * 32;
  int qbaseB = qbaseA + 16;

  const unsigned short* qpA = &qkv[(rowbase + qbaseA + fr) * NQKV + h * 64 + fg * 8];
  const unsigned short* qpB = &qkv[(rowbase + qbaseB + fr) * NQKV + h * 64 + fg * 8];
  bf16x8 qfA0 = *(const bf16x8*)(qpA);
  bf16x8 qfA1 = *(const bf16x8*)(qpA + 32);
  bf16x8 qfB0 = *(const bf16x8*)(qpB);
  bf16x8 qfB1 = *(const bf16x8*)(qpB + 32);

  int kcb = ((t & 7) * 16) ^ (((t >> 3) & 7) << 4);    // K: 128B rows, row = p*32 + (t>>3)
  int vcb = ((t & 15) * 16) ^ (((t >> 4) & 7) << 4);   // V: 256B rows, row = p*16 + (t>>4)

  const char* kgb = (const char*)qkv;
  const char* vgb = (const char*)vT;
  long ksrc0 = ((rowbase) * (long)NQKV + KOFF + (long)g * 64) * 2;
  long vsrc0 = (((long)(b * 512 + g * 64)) * LSEQ) * 2;

  auto stageK = [&](int kbase) {
    #pragma unroll
    for (int p = 0; p < 4; p++) {
      int krow = p * 32 + (t >> 3);
      gload_lds16(kgb + ksrc0 + (long)(kbase + krow) * (NQKV * 2) + kcb,
                  KT + p * 4096 + t * 16);
    }
  };
  auto stageV = [&](int kbase) {
    #pragma unroll
    for (int p = 0; p < 4; p++) {
      int vrow = p * 16 + (t >> 4);
      gload_lds16(vgb + vsrc0 + (long)vrow * (LSEQ * 2) + kbase * 2 + vcb,
                  VT + p * 4096 + t * 16);
    }
  };

  stageK(0);   // K older than V: B1's vmcnt(4) waits K (and Q), leaves V in flight
  stageV(0);

  f32x4 poA[4] = {}, poB[4] = {};
  f32x4 lfA = {}, lfB = {};           // MFMA-accumulated row-sums of P (denominator)
  bf16x8 onesv;
  #pragma unroll
  for (int i = 0; i < 8; i++) onesv[i] = (__bf16)1.0f;

  int sw8 = (fr & 7) << 4;

  for (int kt = 0; kt <= qt; kt++) {
    int kbase = kt * 128;
    // B1: wait K (oldest; +Q at iter 0); V's 4 loads stay in flight across QK.
    asm volatile("s_waitcnt vmcnt(4)" ::: "memory");
    __builtin_amdgcn_s_barrier();
    __builtin_amdgcn_sched_barrier(0);

    f32x4 stA[8], stB[8];
    __builtin_amdgcn_s_setprio(1);
    #pragma unroll
    for (int s = 0; s < 8; s++) {
      const char* kr = KT + ((s * 16 + fr) << 7);
      bf16x8 kf0 = *(const bf16x8*)(kr + ((fg * 16) ^ sw8));
      bf16x8 kf1 = *(const bf16x8*)(kr + ((fg * 16 + 64) ^ sw8));
      f32x4 a = {};
      a = __builtin_amdgcn_mfma_f32_16x16x32_bf16(kf0, qfA0, a, 0, 0, 0);
      a = __builtin_amdgcn_mfma_f32_16x16x32_bf16(kf1, qfA1, a, 0, 0, 0);
      stA[s] = a;
      f32x4 c = {};
      c = __builtin_amdgcn_mfma_f32_16x16x32_bf16(kf0, qfB0, c, 0, 0, 0);
      c = __builtin_amdgcn_mfma_f32_16x16x32_bf16(kf1, qfB1, c, 0, 0, 0);
      stB[s] = c;
    }
    __builtin_amdgcn_s_setprio(0);
    __syncthreads();   // B2: implicit vmcnt(0) drains V; all waves' K reads retired

    if (kt < qt) stageK(kbase + 128);   // K restage WAR-safe past B2; cover = softmax+PV+B3

    if (kt == qt) {   // diagonal tile: causal mask (k = kbase+s*16+fg*4+r, q = qbase+fr)
      #pragma unroll
      for (int s = 0; s < 8; s++) {
        #pragma unroll
        for (int r = 0; r < 4; r++) {
          int kp = kbase + s * 16 + fg * 4 + r;
          if (kp > qbaseA + fr) stA[s][r] = -1e30f;
          if (kp > qbaseB + fr) stB[s][r] = -1e30f;
        }
      }
    }

    // softmax (static-max, pre-scaled exp2 domain) + register-only bf16 pack.
    bf16x8 paA[4], paB[4];
    #pragma unroll
    for (int km = 0; km < 4; km++) {
      bf16x8 pa, pb;
      #pragma unroll
      for (int r = 0; r < 4; r++) {
        pa[r]     = (__bf16)exp2f(stA[2 * km][r]);
        pa[r + 4] = (__bf16)exp2f(stA[2 * km + 1][r]);
        pb[r]     = (__bf16)exp2f(stB[2 * km][r]);
        pb[r + 4] = (__bf16)exp2f(stB[2 * km + 1][r]);
      }
      paA[km] = pa;
      paB[km] = pb;
    }

    __builtin_amdgcn_s_setprio(1);
    #pragma unroll
    for (int km = 0; km < 4; km++) {
      lfA = __builtin_amdgcn_mfma_f32_16x16x32_bf16(paA[km], onesv, lfA, 0, 0, 0);
      lfB = __builtin_amdgcn_mfma_f32_16x16x32_bf16(paB[km], onesv, lfB, 0, 0, 0);
      #pragma unroll
      for (int dt = 0; dt < 4; dt++) {
        const char* vr = VT + ((dt * 16 + fr) << 8);
        bf16x8 vf = *(const bf16x8*)(vr + ((km * 64 + fg * 16) ^ sw8));
        poA[dt] = __builtin_amdgcn_mfma_f32_16x16x32_bf16(paA[km], vf, poA[dt], 0, 0, 0);
        poB[dt] = __builtin_amdgcn_mfma_f32_16x16x32_bf16(paB[km], vf, poB[dt], 0, 0, 0);
      }
    }
    __builtin_amdgcn_s_setprio(0);

    if (kt < qt) {
      __syncthreads();        // B3: all waves' V reads retired -> same-buffer restage safe
      stageV(kbase + 128);    // drains at next iter's B2 (cover: B1 + QK phase)
    }
  }

  // denominator is lane-local: lf[r] = l for q = fg*4+r (identical on every lane's col)
  #pragma unroll
  for (int r = 0; r < 4; r++) {
    float liA = 1.0f / lfA[r];
    float liB = 1.0f / lfB[r];
    #pragma unroll
    for (int dt = 0; dt < 4; dt++) {
      attn[(rowbase + qbaseA + fg * 4 + r) * DIM + h * 64 + dt * 16 + fr] = f2bf(poA[dt][r] * liA);
      attn[(rowbase + qbaseB + fg * 4 + r) * DIM + h * 64 + dt * 16 + fr] = f2bf(poB[dt][r] * liB);
    }
  }
}

extern "C" void kernel_launch(void* const* d_in, const int* in_sizes, int n_in,
                              void* d_out, int out_size, void* d_ws, size_t ws_size,
                              hipStream_t stream) {
  const float* x  = (const float*)d_in[0];
  const float* wq = (const float*)d_in[1];
  const float* wk = (const float*)d_in[2];
  const float* wv = (const float*)d_in[3];
  const float* wo = (const float*)d_in[4];

  char* ws = (char*)d_ws;
  unsigned short* xb    = (unsigned short*)(ws);                 // 16.78 MB (reused as vT later)
  unsigned short* wqkvT = (unsigned short*)(ws + 16777216);      // 12.58 MB [3072][2048]
  unsigned short* woT   = (unsigned short*)(ws + 29360128);      //  8.39 MB [2048][2048]
  unsigned short* qkv   = (unsigned short*)(ws + 37748736);      // 25.17 MB [4096][3072]
  unsigned short* attn  = (unsigned short*)(ws + 62914560);      // 16.78 MB [4096][2048]
  float* cosT           = (float*)(ws + 79691776);               // 256 KB
  float* sinT           = (float*)(ws + 79953920);               // 256 KB
  unsigned short* vT    = xb;                                    // alias: xb dead after QKV GEMM

  const float C2 = 0.125f * 1.44269504f;   // 1/sqrt(64) * log2(e), folded into wq

  k_cvt_x<<<8192, 256, 0, stream>>>(x, xb, M_ROWS * DIM / 4);
  dim3 tb(32, 8);
  // fused weight transposes + RoPE tables: one launch, 5 z-sections
  k_transpose_all<<<dim3(64, 64, 5), tb, 0, stream>>>(wq, wk, wv, wo, wqkvT, woT, cosT, sinT, C2);

  // QKV: 128^2 BK=64, 512 threads / 8 waves (r13-verified) + fused RoPE epilogue
  k_gemm_bt<true, true><<<dim3(M_ROWS/128, NQKV/128), 512, 0, stream>>>(
      xb, wqkvT, qkv, M_ROWS, NQKV, DIM, cosT, sinT);
  k_transpose_v<<<dim3(16, 64, 2), tb, 0, stream>>>(qkv, vT);
  // flash: single-buffered V, 32KB LDS -> 4 blocks/CU
  k_flash_attn17<<<1024, 256, 0, stream>>>(qkv, vT, attn);
  // WO: r13-verified 128^2 dbuf single-barrier pipeline, 512 threads
  k_gemm_db<<<dim3(M_ROWS/128, DIM/128), 512, 0, stream>>>(
      attn, woT, (float*)d_out, M_ROWS, DIM, DIM);
}

// Round 20
// 173.000 us; speedup vs baseline: 1.1597x; 1.1597x over previous
//
#include <hip/hip_runtime.h>
#include <stdint.h>

#define DIM   2048
#define LSEQ  2048
#define BATCH 2
#define NH    32
#define NKV   8
#define HD    64
#define M_ROWS (BATCH*LSEQ)       // 4096
#define NQKV  (DIM + 2*NKV*HD)    // 3072
#define KOFF  DIM                 // 2048
#define VOFF  (DIM + NKV*HD)      // 2560

typedef __attribute__((ext_vector_type(8))) __bf16 bf16x8;
typedef __attribute__((ext_vector_type(8))) unsigned short u16x8;
typedef __attribute__((ext_vector_type(4))) float f32x4;

// hardware RNE f32->bf16 (harness-verified rounds 2-18)
__device__ __forceinline__ unsigned short f2bf(float f) {
  union { __bf16 h; unsigned short u; } v;
  v.h = (__bf16)f;
  return v.u;
}
__device__ __forceinline__ float bf2f(unsigned short h) {
  union { unsigned u; float f; } v; v.u = ((unsigned)h) << 16;
  return v.f;
}

__device__ __forceinline__ void gload_lds16(const void* g, void* l) {
  __builtin_amdgcn_global_load_lds(
      (__attribute__((address_space(1))) unsigned int*)g,
      (__attribute__((address_space(3))) unsigned int*)l, 16, 0, 0);
}

// ---------------- fp32 -> bf16 convert (vectorized) ----------------
__global__ void k_cvt_x(const float* __restrict__ in, unsigned short* __restrict__ out, int n4) {
  int i = blockIdx.x * blockDim.x + threadIdx.x;
  if (i >= n4) return;
  float4 v = ((const float4*)in)[i];
  ushort4 o;
  o.x = f2bf(v.x); o.y = f2bf(v.y); o.z = f2bf(v.z); o.w = f2bf(v.w);
  ((ushort4*)out)[i] = o;
}

// ---------------- fused weight transposes + RoPE tables: 5 z-sections (r18-verified) ----------------
__global__ void k_transpose_all(const float* __restrict__ wq, const float* __restrict__ wk,
                                const float* __restrict__ wv, const float* __restrict__ wo,
                                unsigned short* __restrict__ wqkvT,
                                unsigned short* __restrict__ woT,
                                float* __restrict__ cosT, float* __restrict__ sinT,
                                float C2) {
  int sec = blockIdx.z;
  if (sec == 4) {   // RoPE tables: idx < 256 blocks x 256 threads = LSEQ*32 elements
    int idx = blockIdx.y * 64 + blockIdx.x;
    if (idx >= 256) return;
    int i = idx * 256 + threadIdx.y * 32 + threadIdx.x;
    int tpos = i >> 5, j = i & 31;
    float inv = powf(10000.0f, -(float)j / 32.0f);
    float fr = (float)tpos * inv;
    cosT[i] = cosf(fr);
    sinT[i] = sinf(fr);
    return;
  }
  __shared__ float tile[32][33];
  const float* in; unsigned short* out; int N; float scale = 1.0f;
  if (sec == 0)      { in = wq; out = wqkvT;                     N = DIM; scale = C2; }
  else if (sec == 1) { in = wk; out = wqkvT + (long)2048 * 2048; N = 512; }
  else if (sec == 2) { in = wv; out = wqkvT + (long)2560 * 2048; N = 512; }
  else               { in = wo; out = woT;                       N = DIM; }
  int n0 = blockIdx.x * 32;
  if (n0 >= N) return;
  int k0 = blockIdx.y * 32;
  int tx = threadIdx.x, ty = threadIdx.y;
  #pragma unroll
  for (int i = ty; i < 32; i += 8)
    tile[i][tx] = in[(long)(k0 + i) * N + n0 + tx];
  __syncthreads();
  #pragma unroll
  for (int i = ty; i < 32; i += 8)
    out[(long)(n0 + i) * DIM + k0 + tx] = f2bf(scale * tile[tx][i]);
}

// ---------------- transpose V section of qkv -> vT, k-PERMUTED columns (r6-verified) ----------------
__global__ void k_transpose_v(const unsigned short* __restrict__ qkv,
                              unsigned short* __restrict__ vT) {
  __shared__ unsigned short tile[32][33];
  int c0 = blockIdx.x * 32;   // within 512 (= g*64+d)
  int l0 = blockIdx.y * 32;
  int b  = blockIdx.z;
  int tx = threadIdx.x, ty = threadIdx.y;
  #pragma unroll
  for (int i = ty; i < 32; i += 8)
    tile[i][tx] = qkv[((long)b * LSEQ + l0 + i) * NQKV + VOFF + c0 + tx];
  __syncthreads();
  int e = 8 * ((tx >> 2) & 3) + 4 * (tx >> 4) + (tx & 3);
  #pragma unroll
  for (int i = ty; i < 32; i += 8)
    vT[((long)b * 512 + c0 + i) * LSEQ + l0 + e] = tile[tx][i];
}

// ---------------- GEMM v8 (QKV): 128^2 tile, BK=64, 512 thr / 8 waves (r13-verified) ----------------
template<bool BF16OUT, bool ROPE>
__global__ __launch_bounds__(512, 4) void k_gemm_bt(
    const unsigned short* __restrict__ A, const unsigned short* __restrict__ Bt,
    void* __restrict__ Cv, int M, int N, int K,
    const float* __restrict__ cosT, const float* __restrict__ sinT) {
  __shared__ __align__(16) char AsB[16384];   // [128 rows][128B], swizzled
  __shared__ __align__(16) char BsB[16384];
  int t = threadIdx.x;
  int lane = t & 63, wave = t >> 6;        // 0..7
  int fr = lane & 15, fg = lane >> 4;
  int wm = wave >> 1, wn = wave & 1;       // 4M x 2N quadrants: 32 rows x 64 cols
  long rowA = (long)blockIdx.x * 128;
  long rowB = (long)blockIdx.y * 128;
  long K2 = (long)K * 2;

  int scol = ((t & 7) * 16) ^ (((t >> 3) & 7) << 4);
  const char* ApB = (const char*)A  + (rowA + (t >> 3)) * K2 + scol;
  const char* BpB = (const char*)Bt + (rowB + (t >> 3)) * K2 + scol;

  f32x4 acc[2][4] = {};
  int sw8 = (fr & 7) << 4;

  for (int kt = 0; kt < K; kt += 64) {
    #pragma unroll
    for (int p = 0; p < 2; p++) {
      gload_lds16(ApB + (long)(p * 64) * K2 + kt * 2, AsB + p * 8192 + t * 16);
      gload_lds16(BpB + (long)(p * 64) * K2 + kt * 2, BsB + p * 8192 + t * 16);
    }
    __syncthreads();
    #pragma unroll
    for (int ks = 0; ks < 2; ks++) {
      bf16x8 af[2], bfv[4];
      #pragma unroll
      for (int i = 0; i < 2; i++)
        af[i] = *(const bf16x8*)(AsB + (wm * 32 + i * 16 + fr) * 128 + ((ks * 64 + fg * 16) ^ sw8));
      #pragma unroll
      for (int j = 0; j < 4; j++)
        bfv[j] = *(const bf16x8*)(BsB + (wn * 64 + j * 16 + fr) * 128 + ((ks * 64 + fg * 16) ^ sw8));
      #pragma unroll
      for (int i = 0; i < 2; i++) {
        #pragma unroll
        for (int j = 0; j < 4; j++)
          acc[i][j] = __builtin_amdgcn_mfma_f32_16x16x32_bf16(af[i], bfv[j], acc[i][j], 0, 0, 0);
      }
    }
    __syncthreads();
  }

  long colbase = rowB + wn * 64;
  bool rope_sec = ROPE && (colbase < VOFF);   // Q or K head (col < 2560); wave-uniform
  #pragma unroll
  for (int i = 0; i < 2; i++) {
    #pragma unroll
    for (int r = 0; r < 4; r++) {
      long row = rowA + wm * 32 + i * 16 + fg * 4 + r;
      if (ROPE && rope_sec) {
        int tpos = (int)(row & (LSEQ - 1));
        #pragma unroll
        for (int j = 0; j < 2; j++) {   // pair (d = j*16+fr, d+32 = (j+2)*16+fr)
          int jj = j * 16 + fr;
          float c = cosT[tpos * 32 + jj];
          float s = sinT[tpos * 32 + jj];
          float lo = acc[i][j][r], hi = acc[i][j + 2][r];
          ((unsigned short*)Cv)[row * N + colbase + j * 16 + fr]       = f2bf(lo * c - hi * s);
          ((unsigned short*)Cv)[row * N + colbase + (j + 2) * 16 + fr] = f2bf(hi * c + lo * s);
        }
      } else {
        #pragma unroll
        for (int j = 0; j < 4; j++) {
          long col = colbase + j * 16 + fr;
          if (BF16OUT) ((unsigned short*)Cv)[row * N + col] = f2bf(acc[i][j][r]);
          else         ((float*)Cv)[row * N + col] = acc[i][j][r];
        }
      }
    }
  }
}

// ---------------- GEMM v9 (WO): 128^2 dbuf single-barrier pipeline, 512 threads (r13-verified) ----------------
__global__ __launch_bounds__(512, 4) void k_gemm_db(
    const unsigned short* __restrict__ A, const unsigned short* __restrict__ Bt,
    float* __restrict__ Cv, int M, int N, int K) {
  __shared__ __align__(16) char AsB[2][16384];   // [buf][128 rows][128B], swizzled
  __shared__ __align__(16) char BsB[2][16384];
  int t = threadIdx.x;
  int lane = t & 63, wave = t >> 6;
  int fr = lane & 15, fg = lane >> 4;
  int wm = wave >> 1, wn = wave & 1;       // 4M x 2N quadrants: 32 rows x 64 cols
  long rowA = (long)blockIdx.x * 128;
  long rowB = (long)blockIdx.y * 128;
  long K2 = (long)K * 2;

  int scol = ((t & 7) * 16) ^ (((t >> 3) & 7) << 4);
  const char* ApB = (const char*)A  + (rowA + (t >> 3)) * K2 + scol;
  const char* BpB = (const char*)Bt + (rowB + (t >> 3)) * K2 + scol;

  auto stage = [&](int kt, int bi) {   // kt in 64-elem tiles; 4 loads/thread
    #pragma unroll
    for (int p = 0; p < 2; p++) {
      gload_lds16(ApB + (long)(p * 64) * K2 + (long)kt * 128, AsB[bi] + p * 8192 + t * 16);
      gload_lds16(BpB + (long)(p * 64) * K2 + (long)kt * 128, BsB[bi] + p * 8192 + t * 16);
    }
  };

  f32x4 acc[2][4] = {};
  int sw8 = (fr & 7) << 4;
  int NT = K >> 6;

  stage(0, 0);
  for (int kt = 0; kt < NT; kt++) {
    int cur = kt & 1;
    // tile kt's 4 loads are the only outstanding VMEM; issued a full iteration ago
    asm volatile("s_waitcnt vmcnt(0)" ::: "memory");
    __builtin_amdgcn_s_barrier();
    __builtin_amdgcn_sched_barrier(0);
    const char* Ac = AsB[cur];
    const char* Bc = BsB[cur];
    #pragma unroll
    for (int ks = 0; ks < 2; ks++) {
      bf16x8 af[2], bfv[4];
      #pragma unroll
      for (int i = 0; i < 2; i++)
        af[i] = *(const bf16x8*)(Ac + (wm * 32 + i * 16 + fr) * 128 + ((ks * 64 + fg * 16) ^ sw8));
      #pragma unroll
      for (int j = 0; j < 4; j++)
        bfv[j] = *(const bf16x8*)(Bc + (wn * 64 + j * 16 + fr) * 128 + ((ks * 64 + fg * 16) ^ sw8));
      if (ks == 0 && kt + 1 < NT) stage(kt + 1, cur ^ 1);   // issue under reads+MFMA
      #pragma unroll
      for (int i = 0; i < 2; i++) {
        #pragma unroll
        for (int j = 0; j < 4; j++)
          acc[i][j] = __builtin_amdgcn_mfma_f32_16x16x32_bf16(af[i], bfv[j], acc[i][j], 0, 0, 0);
      }
    }
  }

  #pragma unroll
  for (int i = 0; i < 2; i++) {
    #pragma unroll
    for (int j = 0; j < 4; j++) {
      #pragma unroll
      for (int r = 0; r < 4; r++) {
        long row = rowA + wm * 32 + i * 16 + fg * 4 + r;
        long col = rowB + wn * 64 + j * 16 + fr;
        Cv[row * N + col] = acc[i][j][r];
      }
    }
  }
}

// ---------------- flash attention v17 (r14-verified, 64.5us; FINAL) ----------------
// 4-wave, 128 q-rows/block, launch_bounds(256,3) -- the ONLY configuration that keeps
// this dataflow in registers (VGPR 84). Tighter caps ((256,4), 512-thread variants)
// all collapsed to 64-VGPR spilled solutions (r15/r16/r19): the kernel needs ~150 VGPR
// of transient scheduling headroom. Loop-uniform causal mask (kt==qt) is load-bearing.
// Swapped QK (mfma(K,Q)) -> P lane-local; register-only bf16 pack; permuted-V;
// static-max softmax (wq pre-scaled into exp2 domain); ones-MFMA denominator.
__global__ __launch_bounds__(256, 3) void k_flash_attn14(
    const unsigned short* __restrict__ qkv, const unsigned short* __restrict__ vT,
    unsigned short* __restrict__ attn) {
  int g0 = (int)blockIdx.x;
  int hb = g0 & 63;
  int h = hb & 31, b = hb >> 5;
  int qt = 15 - (g0 >> 6);            // heavy blocks first (backfill smooths the tail)
  int g = h >> 2;
  int t = threadIdx.x, lane = t & 63, wave = t >> 6;
  int fr = lane & 15, fg = lane >> 4;

  __shared__ __align__(16) char KT[16384];              // 16KB: K tile [128 rows][128B], swz
  __shared__ __align__(16) char VT2[2][16384];          // 32KB: V tile [64 rows][256B], swz, dbuf
  long rowbase = (long)b * LSEQ;

  int qbaseA = qt * 128 + wave * 32;
  int qbaseB = qbaseA + 16;

  const unsigned short* qpA = &qkv[(rowbase + qbaseA + fr) * NQKV + h * 64 + fg * 8];
  const unsigned short* qpB = &qkv[(rowbase + qbaseB + fr) * NQKV + h * 64 + fg * 8];
  bf16x8 qfA0 = *(const bf16x8*)(qpA);
  bf16x8 qfA1 = *(const bf16x8*)(qpA + 32);
  bf16x8 qfB0 = *(const bf16x8*)(qpB);
  bf16x8 qfB1 = *(const bf16x8*)(qpB + 32);

  int kcb = ((t & 7) * 16) ^ (((t >> 3) & 7) << 4);    // K: 128B rows, row = p*32 + (t>>3)
  int vcb = ((t & 15) * 16) ^ (((t >> 4) & 7) << 4);   // V: 256B rows, row = p*16 + (t>>4)

  const char* kgb = (const char*)qkv;
  const char* vgb = (const char*)vT;
  long ksrc0 = ((rowbase) * (long)NQKV + KOFF + (long)g * 64) * 2;
  long vsrc0 = (((long)(b * 512 + g * 64)) * LSEQ) * 2;

  auto stageK = [&](int kbase) {
    #pragma unroll
    for (int p = 0; p < 4; p++) {
      int krow = p * 32 + (t >> 3);
      gload_lds16(kgb + ksrc0 + (long)(kbase + krow) * (NQKV * 2) + kcb,
                  KT + p * 4096 + t * 16);
    }
  };
  auto stageV = [&](int kbase, char* dst) {
    #pragma unroll
    for (int p = 0; p < 4; p++) {
      int vrow = p * 16 + (t >> 4);
      gload_lds16(vgb + vsrc0 + (long)vrow * (LSEQ * 2) + kbase * 2 + vcb,
                  dst + p * 4096 + t * 16);
    }
  };

  stageK(0);
  stageV(0, VT2[0]);

  f32x4 poA[4] = {}, poB[4] = {};
  f32x4 lfA = {}, lfB = {};           // MFMA-accumulated row-sums of P (denominator)
  bf16x8 onesv;
  #pragma unroll
  for (int i = 0; i < 8; i++) onesv[i] = (__bf16)1.0f;

  int sw8 = (fr & 7) << 4;

  for (int kt = 0; kt <= qt; kt++) {
    int kbase = kt * 128;
    __syncthreads();   // B1: staged K/V landed; all waves' prev-iter LDS reads done

    // V restage WAR-safe at B1 (prev PV readers of this buffer synced); full-iter cover
    if (kt < qt) stageV(kbase + 128, VT2[(kt + 1) & 1]);

    f32x4 stA[8], stB[8];
    __builtin_amdgcn_s_setprio(1);
    #pragma unroll
    for (int s = 0; s < 8; s++) {
      const char* kr = KT + ((s * 16 + fr) << 7);
      bf16x8 kf0 = *(const bf16x8*)(kr + ((fg * 16) ^ sw8));
      bf16x8 kf1 = *(const bf16x8*)(kr + ((fg * 16 + 64) ^ sw8));
      f32x4 a = {};
      a = __builtin_amdgcn_mfma_f32_16x16x32_bf16(kf0, qfA0, a, 0, 0, 0);
      a = __builtin_amdgcn_mfma_f32_16x16x32_bf16(kf1, qfA1, a, 0, 0, 0);
      stA[s] = a;
      f32x4 c = {};
      c = __builtin_amdgcn_mfma_f32_16x16x32_bf16(kf0, qfB0, c, 0, 0, 0);
      c = __builtin_amdgcn_mfma_f32_16x16x32_bf16(kf1, qfB1, c, 0, 0, 0);
      stB[s] = c;
    }
    __builtin_amdgcn_s_setprio(0);
    __syncthreads();   // B2: all waves' K ds_reads retired -> K restage safe

    if (kt < qt) stageK(kbase + 128);   // lands by next B1; softmax+PV cover

    if (kt == qt) {   // diagonal tile: causal mask (k = kbase+s*16+fg*4+r, q = qbase+fr)
      #pragma unroll
      for (int s = 0; s < 8; s++) {
        #pragma unroll
        for (int r = 0; r < 4; r++) {
          int kp = kbase + s * 16 + fg * 4 + r;
          if (kp > qbaseA + fr) stA[s][r] = -1e30f;
          if (kp > qbaseB + fr) stB[s][r] = -1e30f;
        }
      }
    }

    // softmax (static-max, pre-scaled exp2 domain) + register-only bf16 pack.
    // A-frag slot (fg, j): j=r -> k32 = 4*fg + r ; j=4+r -> k32 = 16 + 4*fg + r.
    bf16x8 paA[4], paB[4];
    #pragma unroll
    for (int km = 0; km < 4; km++) {
      bf16x8 pa, pb;
      #pragma unroll
      for (int r = 0; r < 4; r++) {
        pa[r]     = (__bf16)exp2f(stA[2 * km][r]);
        pa[r + 4] = (__bf16)exp2f(stA[2 * km + 1][r]);
        pb[r]     = (__bf16)exp2f(stB[2 * km][r]);
        pb[r + 4] = (__bf16)exp2f(stB[2 * km + 1][r]);
      }
      paA[km] = pa;
      paB[km] = pb;
    }

    const char* Vb = VT2[kt & 1];
    __builtin_amdgcn_s_setprio(1);
    #pragma unroll
    for (int km = 0; km < 4; km++) {
      lfA = __builtin_amdgcn_mfma_f32_16x16x32_bf16(paA[km], onesv, lfA, 0, 0, 0);
      lfB = __builtin_amdgcn_mfma_f32_16x16x32_bf16(paB[km], onesv, lfB, 0, 0, 0);
      #pragma unroll
      for (int dt = 0; dt < 4; dt++) {
        const char* vr = Vb + ((dt * 16 + fr) << 8);
        bf16x8 vf = *(const bf16x8*)(vr + ((km * 64 + fg * 16) ^ sw8));
        poA[dt] = __builtin_amdgcn_mfma_f32_16x16x32_bf16(paA[km], vf, poA[dt], 0, 0, 0);
        poB[dt] = __builtin_amdgcn_mfma_f32_16x16x32_bf16(paB[km], vf, poB[dt], 0, 0, 0);
      }
    }
    __builtin_amdgcn_s_setprio(0);
    // no trailing barrier: next B1 orders LDS reads vs. restaging
  }

  // denominator is lane-local: lf[r] = l for q = fg*4+r (identical on every lane's col)
  #pragma unroll
  for (int r = 0; r < 4; r++) {
    float liA = 1.0f / lfA[r];
    float liB = 1.0f / lfB[r];
    #pragma unroll
    for (int dt = 0; dt < 4; dt++) {
      attn[(rowbase + qbaseA + fg * 4 + r) * DIM + h * 64 + dt * 16 + fr] = f2bf(poA[dt][r] * liA);
      attn[(rowbase + qbaseB + fg * 4 + r) * DIM + h * 64 + dt * 16 + fr] = f2bf(poB[dt][r] * liB);
    }
  }
}

extern "C" void kernel_launch(void* const* d_in, const int* in_sizes, int n_in,
                              void* d_out, int out_size, void* d_ws, size_t ws_size,
                              hipStream_t stream) {
  const float* x  = (const float*)d_in[0];
  const float* wq = (const float*)d_in[1];
  const float* wk = (const float*)d_in[2];
  const float* wv = (const float*)d_in[3];
  const float* wo = (const float*)d_in[4];

  char* ws = (char*)d_ws;
  unsigned short* xb    = (unsigned short*)(ws);                 // 16.78 MB (reused as vT later)
  unsigned short* wqkvT = (unsigned short*)(ws + 16777216);      // 12.58 MB [3072][2048]
  unsigned short* woT   = (unsigned short*)(ws + 29360128);      //  8.39 MB [2048][2048]
  unsigned short* qkv   = (unsigned short*)(ws + 37748736);      // 25.17 MB [4096][3072]
  unsigned short* attn  = (unsigned short*)(ws + 62914560);      // 16.78 MB [4096][2048]
  float* cosT           = (float*)(ws + 79691776);               // 256 KB
  float* sinT           = (float*)(ws + 79953920);               // 256 KB
  unsigned short* vT    = xb;                                    // alias: xb dead after QKV GEMM

  const float C2 = 0.125f * 1.44269504f;   // 1/sqrt(64) * log2(e), folded into wq

  k_cvt_x<<<8192, 256, 0, stream>>>(x, xb, M_ROWS * DIM / 4);
  dim3 tb(32, 8);
  // fused weight transposes + RoPE tables: one launch, 5 z-sections
  k_transpose_all<<<dim3(64, 64, 5), tb, 0, stream>>>(wq, wk, wv, wo, wqkvT, woT, cosT, sinT, C2);

  // QKV: 128^2 BK=64, 512 threads / 8 waves (r13-verified) + fused RoPE epilogue
  k_gemm_bt<true, true><<<dim3(M_ROWS/128, NQKV/128), 512, 0, stream>>>(
      xb, wqkvT, qkv, M_ROWS, NQKV, DIM, cosT, sinT);
  k_transpose_v<<<dim3(16, 64, 2), tb, 0, stream>>>(qkv, vT);
  // flash: r14-verified 4-wave kernel (64.5us; launch_bounds(256,3) is load-bearing)
  k_flash_attn14<<<1024, 256, 0, stream>>>(qkv, vT, attn);
  // WO: r13-verified 128^2 dbuf single-barrier pipeline, 512 threads
  k_gemm_db<<<dim3(M_ROWS/128, DIM/128), 512, 0, stream>>>(
      attn, woT, (float*)d_out, M_ROWS, DIM, DIM);
}